// Round 11
// baseline (165.462 us; speedup 1.0000x reference)
//
#include <hip/hip_runtime.h>
#include <hip/hip_fp16.h>

typedef _Float16 f16;
typedef unsigned int u32;
typedef _Float16 f16x4 __attribute__((ext_vector_type(4)));
typedef _Float16 f16x8 __attribute__((ext_vector_type(8)));
typedef float f32x4 __attribute__((ext_vector_type(4)));
typedef float f32x16 __attribute__((ext_vector_type(16)));

#define B_  2
#define N_  2048
#define C_  1024
#define H_  16
#define HD_ 64

// ---------------------------------------------------------------- helpers
__device__ __forceinline__ void gload_lds16(const void* g, void* l) {
  __builtin_amdgcn_global_load_lds((const __attribute__((address_space(1))) u32*)g,
                                   (__attribute__((address_space(3))) u32*)l,
                                   16, 0, 0);
}

__device__ __forceinline__ u32 pack_f16(float a, float b) {
  auto h2 = __builtin_amdgcn_cvt_pkrtz(a, b);   // __fp16 ext_vector(2)
  return __builtin_bit_cast(u32, h2);
}

__device__ __forceinline__ float max3f(float a, float b, float c) {
  return fmaxf(fmaxf(a, b), c);   // clang fuses to v_max3_f32
}

// ---------------------------------------------------------------- mask dtype probe
__global__ void detect_mask(const u32* __restrict__ m, int* __restrict__ flag) {
  __shared__ int bad;
  if (threadIdx.x == 0) bad = 0;
  __syncthreads();
  int v = 0;
  for (int i = threadIdx.x; i < 1024; i += 256) {
    u32 w = m[i];
    if (w != 0u && w != 1u && w != 0x3F800000u) v = 1;
  }
  if (v) atomicOr(&bad, 1);
  __syncthreads();
  if (threadIdx.x == 0) *flag = bad;   // 1 => byte mask, 0 => 4-byte mask
}

// ---------------------------------------------------------------- phase table
__global__ __launch_bounds__(256) void phase_tab(const float* __restrict__ px,
                                                 const float* __restrict__ py,
                                                 const float* __restrict__ psp,
                                                 const void* __restrict__ maskPtr,
                                                 const int* __restrict__ maskFlag,
                                                 float* __restrict__ cs_tab,
                                                 float* __restrict__ sn_tab) {
  const int idx = blockIdx.x * 256 + threadIdx.x;   // (b*N+n)*32 + j
  const int j = idx & 31, tn = idx >> 5;
  const int byteMode = *maskFlag;
  const bool doRope = byteMode ? (((const unsigned char*)maskPtr)[tn] != 0)
                               : (((const u32*)maskPtr)[tn] != 0u);
  float c = 1.f, s = 0.f;
  if (doRope) {
    float ph;
    if (j < 12)      ph = px[tn * 12 + j];
    else if (j < 24) ph = py[tn * 12 + (j - 12)];
    else             ph = psp[tn * 8 + (j - 24)];
    c = __cosf(ph);
    s = __sinf(ph);
  }
  cs_tab[idx] = c;
  sn_tab[idx] = s;
}

// ---------------------------------------------------------------- x f32 -> f16
__global__ __launch_bounds__(256) void cvt_x(const float* __restrict__ in,
                                             f16* __restrict__ out, int n8) {
  const int i = blockIdx.x * 256 + threadIdx.x;
  if (i >= n8) return;
  const float4 a = ((const float4*)in)[i * 2];
  const float4 b = ((const float4*)in)[i * 2 + 1];
  f16x8 o = {(f16)a.x, (f16)a.y, (f16)a.z, (f16)a.w,
             (f16)b.x, (f16)b.y, (f16)b.z, (f16)b.w};
  ((f16x8*)out)[i] = o;
}

// ---------------------------------------------------------------- W (RxC f32) -> Wt (CxR f16)
__global__ __launch_bounds__(256) void transpose_cvt(const float* __restrict__ W,
                                                     f16* __restrict__ Wt,
                                                     int R, int Ccols) {
  __shared__ __align__(16) f16 tile[32][34];
  const int c0 = blockIdx.x * 32, r0 = blockIdx.y * 32;
  const int tx = threadIdx.x, ty = threadIdx.y;  // 32 x 8
#pragma unroll
  for (int k = 0; k < 4; ++k)
    tile[ty + 8 * k][tx] = (f16)W[(size_t)(r0 + ty + 8 * k) * Ccols + c0 + tx];
  __syncthreads();
#pragma unroll
  for (int k = 0; k < 4; ++k)
    Wt[(size_t)(c0 + ty + 8 * k) * R + r0 + tx] = tile[tx][ty + 8 * k];
}

// ---------------------------------------------------------------- GEMM  C = A(MxK) * Bt(NxK)^T + bias
template <bool OUT_F32>
__global__ __launch_bounds__(256) void gemm_bt(const f16* __restrict__ A,
                                               const f16* __restrict__ Bt,
                                               const float* __restrict__ bias,
                                               void* __restrict__ Cout,
                                               int M, int N, int K) {
  __shared__ __align__(16) f16 As[128 * 64];
  __shared__ __align__(16) f16 Bs[128 * 64];
  const int tid = threadIdx.x;
  const int lane = tid & 63;
  const int wv = tid >> 6;
  const int wm = wv >> 1, wn = wv & 1;
  const int nTN = N >> 7;
  int bid = blockIdx.x;
  const int cpx = gridDim.x >> 3;
  bid = (bid & 7) * cpx + (bid >> 3);
  const int tM = bid / nTN, tN = bid % nTN;
  const int rowBase = tM << 7, colBase = tN << 7;
  const int cl = lane & 15, cg = lane >> 4;

  f32x4 acc[4][4];
#pragma unroll
  for (int i = 0; i < 4; ++i)
#pragma unroll
    for (int j = 0; j < 4; ++j) acc[i][j] = (f32x4){0.f, 0.f, 0.f, 0.f};

  const int sR = tid >> 3, sC = tid & 7;

  for (int k0 = 0; k0 < K; k0 += 64) {
#pragma unroll
    for (int is = 0; is < 4; ++is) {
      const int r = is * 32 + sR;
      const int sc = sC ^ (r & 7);
      gload_lds16(A + (size_t)(rowBase + r) * K + k0 + sc * 8, As + is * 2048 + tid * 8);
    }
#pragma unroll
    for (int is = 0; is < 4; ++is) {
      const int r = is * 32 + sR;
      const int sc = sC ^ (r & 7);
      gload_lds16(Bt + (size_t)(colBase + r) * K + k0 + sc * 8, Bs + is * 2048 + tid * 8);
    }
    asm volatile("s_waitcnt vmcnt(0)" ::: "memory");
    __syncthreads();

#pragma unroll
    for (int ks = 0; ks < 2; ++ks) {
      f16x8 af[4], bf[4];
#pragma unroll
      for (int m = 0; m < 4; ++m) {
        const int row = wm * 64 + m * 16 + cl;
        const int ck = (ks * 4 + cg) ^ (row & 7);
        af[m] = *(const f16x8*)(As + row * 64 + ck * 8);
      }
#pragma unroll
      for (int n = 0; n < 4; ++n) {
        const int row = wn * 64 + n * 16 + cl;
        const int ck = (ks * 4 + cg) ^ (row & 7);
        bf[n] = *(const f16x8*)(Bs + row * 64 + ck * 8);
      }
#pragma unroll
      for (int m = 0; m < 4; ++m)
#pragma unroll
        for (int n = 0; n < 4; ++n)
          acc[m][n] = __builtin_amdgcn_mfma_f32_16x16x32_f16(af[m], bf[n], acc[m][n], 0, 0, 0);
    }
    __syncthreads();
  }

#pragma unroll
  for (int m = 0; m < 4; ++m) {
#pragma unroll
    for (int n = 0; n < 4; ++n) {
      const int gr0 = rowBase + wm * 64 + m * 16 + cg * 4;
      const int gc = colBase + wn * 64 + n * 16 + cl;
      const float bz = bias[gc];
#pragma unroll
      for (int reg = 0; reg < 4; ++reg) {
        const float v = acc[m][n][reg] + bz;
        if (OUT_F32)
          ((float*)Cout)[(size_t)(gr0 + reg) * N + gc] = v;
        else
          ((f16*)Cout)[(size_t)(gr0 + reg) * N + gc] = (f16)v;
      }
    }
  }
}

// ---------------------------------------------------------------- RoPE + split (table-driven)
__global__ __launch_bounds__(256) void rope_split(const f16* __restrict__ qkv,
                                                  const float* __restrict__ cs_tab,
                                                  const float* __restrict__ sn_tab,
                                                  f16* __restrict__ Qh,
                                                  f16* __restrict__ Kh,
                                                  f16* __restrict__ Vt) {
  __shared__ float cs[64][32], sn[64][32];
  __shared__ __align__(16) f16 vtile[64][72];
  const int tid = threadIdx.x;
  const int blk = blockIdx.x;
  const int hg = blk & 3;
  const int nt = (blk >> 2) & 31;
  const int b = blk >> 7;
  const int n0 = nt * 64;

  for (int i = tid; i < 64 * 32; i += 256) {
    const int tk = i >> 5, j = i & 31;
    const size_t gi = ((size_t)b * N_ + n0 + tk) * 32 + j;
    cs[tk][j] = cs_tab[gi];
    sn[tk][j] = sn_tab[gi];
  }
  __syncthreads();

  const int tk = tid >> 2, hl = tid & 3;
  const int h = hg * 4 + hl;
  const int n = n0 + tk;
  const size_t inRow = ((size_t)b * N_ + n) * 3072 + (size_t)h * 64;
  const size_t outRow = (((size_t)(b * H_ + h)) * N_ + n) * 64;

#pragma unroll
  for (int sec = 0; sec < 2; ++sec) {
    const f16* src = qkv + inRow + sec * 1024;
    float t[64];
#pragma unroll
    for (int c = 0; c < 8; ++c) {
      f16x8 v = *(const f16x8*)(src + c * 8);
#pragma unroll
      for (int j = 0; j < 8; ++j) t[c * 8 + j] = (float)v[j];
    }
    __align__(16) f16 o[64];
#pragma unroll
    for (int d = 0; d < 64; ++d) {
      int j;
      float rot;
      if (d < 24) {
        j = (d < 12) ? d : d - 12;
        rot = (d < 12) ? -t[d + 12] : t[d - 12];
      } else if (d < 48) {
        const int dd = d - 24;
        j = 12 + ((dd < 12) ? dd : dd - 12);
        rot = (dd < 12) ? -t[d + 12] : t[d - 12];
      } else {
        const int dd = d - 48;
        j = 24 + ((dd < 8) ? dd : dd - 8);
        rot = (dd < 8) ? -t[d + 8] : t[d - 8];
      }
      o[d] = (f16)(t[d] * cs[tk][j] + rot * sn[tk][j]);
    }
    f16* dst = (sec == 0 ? Qh : Kh) + outRow;
#pragma unroll
    for (int c = 0; c < 8; ++c) *(f16x8*)(dst + c * 8) = *(const f16x8*)(o + c * 8);
  }

  for (int hl2 = 0; hl2 < 4; ++hl2) {
    const int h2 = hg * 4 + hl2;
    __syncthreads();
    {
      const int tk2 = tid >> 2, c2 = tid & 3;
      const size_t srow = ((size_t)b * N_ + n0 + tk2) * 3072 + 2048 + (size_t)h2 * 64 + c2 * 16;
      *(f16x8*)(&vtile[tk2][c2 * 16]) = *(const f16x8*)(qkv + srow);
      *(f16x8*)(&vtile[tk2][c2 * 16 + 8]) = *(const f16x8*)(qkv + srow + 8);
    }
    __syncthreads();
    {
      const int d = tid >> 2, seg = tid & 3;
      __align__(16) f16 tmp[16];
#pragma unroll
      for (int i = 0; i < 16; ++i) tmp[i] = vtile[seg * 16 + i][d];
      const size_t drow = (((size_t)(b * H_ + h2)) * 64 + d) * N_ + n0 + seg * 16;
      *(f16x8*)(Vt + drow) = *(const f16x8*)(tmp);
      *(f16x8*)(Vt + drow + 8) = *(const f16x8*)(tmp + 8);
    }
  }
}

// ---------------------------------------------------------------- flash attention v4
// 128-thread blocks (2 waves x 32 q-rows), grid 1024 -> 4 independent barrier
// domains per CU (was 2). Per-lane l accumulation; single cross-half l-reduce
// in epilogue (removes 1 shfl/chunk from critical path). m_run stays shared
// (pmax shfl kept — lanes l,l^32 hold disjoint key-slices of the same q-row).
__global__ __launch_bounds__(128) void attn2(const f16* __restrict__ Qh,
                                             const f16* __restrict__ Kh,
                                             const f16* __restrict__ Vt,
                                             f16* __restrict__ Y) {
  __shared__ __align__(16) f16 lds[2][2][4096];  // [buf][K/V][64*64]
  const int tid = threadIdx.x, lane = tid & 63, w = tid >> 6;
  int bid = blockIdx.x;
  bid = (bid & 7) * 128 + (bid >> 3);  // XCD-chunked swizzle (1024 % 8 == 0)
  const int bh = bid >> 5, qb = bid & 31;   // 32 q-blocks of 64 rows
  const int b = bh >> 4, h = bh & 15;
  const f16* Qb = Qh + (size_t)bh * N_ * 64;
  const f16* Kb = Kh + (size_t)bh * N_ * 64;
  const f16* Vb = Vt + (size_t)bh * 64 * N_;
  const int ql = lane & 31, hi = lane >> 5;

  f16x8 qf[4];
  {
    const int qrow = qb * 64 + w * 32 + ql;
    const f16 scl = (f16)0.125f;
#pragma unroll
    for (int ks = 0; ks < 4; ++ks) {
      f16x8 v = *(const f16x8*)(Qb + (size_t)qrow * 64 + ks * 16 + hi * 8);
#pragma unroll
      for (int j = 0; j < 8; ++j) v[j] *= scl;
      qf[ks] = v;
    }
  }

  f32x16 Of[2];
#pragma unroll
  for (int d = 0; d < 2; ++d)
#pragma unroll
    for (int r = 0; r < 16; ++r) Of[d][r] = 0.f;
  float m_run = -1e30f, l_run = 0.f;   // l_run is PER-LANE (half-row partial)

  const int sr = tid >> 3, sc = tid & 7;   // 16 rows x 8 chunks per pass, 4 passes
#define STAGE(t, bb)                                                                     \
  {                                                                                      \
    _Pragma("unroll") for (int i = 0; i < 4; ++i) {                                      \
      const int row = i * 16 + sr;                                                       \
      const int g = sc ^ (row & 7);                                                      \
      gload_lds16(Kb + (size_t)((t) * 64 + row) * 64 + g * 8,                            \
                  &lds[bb][0][i * 1024 + tid * 8]);                                      \
    }                                                                                    \
    _Pragma("unroll") for (int i = 0; i < 4; ++i) {                                      \
      const int row = i * 16 + sr;                                                       \
      const int g = sc ^ (row & 7);                                                      \
      gload_lds16(Vb + (size_t)row * N_ + (t) * 64 + g * 8,                              \
                  &lds[bb][1][i * 1024 + tid * 8]);                                      \
    }                                                                                    \
  }

#define SOFTMAX_CHUNK(sa)                                                                \
  {                                                                                      \
    float t0 = max3f(sa[0], sa[1], sa[2]);                                               \
    float t1 = max3f(sa[3], sa[4], sa[5]);                                               \
    float t2 = max3f(sa[6], sa[7], sa[8]);                                               \
    float t3 = max3f(sa[9], sa[10], sa[11]);                                             \
    float t4 = max3f(sa[12], sa[13], sa[14]);                                            \
    float pmax = max3f(max3f(t0, t1, t2), max3f(t3, t4, sa[15]), -1e30f);                \
    pmax = fmaxf(pmax, __shfl_xor(pmax, 32));                                            \
    if (__any(pmax > m_run + 8.0f)) {                                                    \
      const float mnew = fmaxf(m_run, pmax);                                             \
      const float corr = __expf(m_run - mnew);                                           \
      l_run *= corr;                                                                     \
      _Pragma("unroll") for (int d = 0; d < 2; ++d)                                      \
        _Pragma("unroll") for (int r = 0; r < 16; ++r) Of[d][r] *= corr;                 \
      m_run = mnew;                                                                      \
    }                                                                                    \
    _Pragma("unroll") for (int r = 0; r < 16; ++r) sa[r] = __expf(sa[r] - m_run);        \
    float s0 = ((sa[0] + sa[1]) + (sa[2] + sa[3])) + ((sa[4] + sa[5]) + (sa[6] + sa[7]));\
    float s1 = ((sa[8] + sa[9]) + (sa[10] + sa[11])) +                                   \
               ((sa[12] + sa[13]) + (sa[14] + sa[15]));                                  \
    l_run += s0 + s1;  /* per-lane partial; cross-half reduce deferred */                \
  }

#define PV_CHUNK(sa, s)                                                                  \
  {                                                                                      \
    u32 pw[8];                                                                           \
    _Pragma("unroll") for (int tt = 0; tt < 8; ++tt)                                     \
      pw[tt] = pack_f16(sa[2 * tt], sa[2 * tt + 1]);                                     \
    _Pragma("unroll") for (int kk = 0; kk < 2; ++kk) {                                   \
      u32 a0 = pw[4 * kk], a1 = pw[4 * kk + 1];                                          \
      u32 b0 = pw[4 * kk + 2], b1 = pw[4 * kk + 3];                                      \
      asm volatile("v_permlane32_swap_b32 %0, %1" : "+v"(a0), "+v"(b0));                 \
      asm volatile("v_permlane32_swap_b32 %0, %1" : "+v"(a1), "+v"(b1));                 \
      union { u32 u[4]; f16x8 v; } pf;                                                   \
      pf.u[0] = a0; pf.u[1] = a1; pf.u[2] = b0; pf.u[3] = b1;                            \
      __builtin_amdgcn_s_setprio(1);                                                     \
      _Pragma("unroll") for (int df = 0; df < 2; ++df) {                                 \
        const int d = df * 32 + ql;                                                      \
        f16x8 vf = *(const f16x8*)(Vs + d * 64 + (((s) * 4 + kk * 2 + hi) ^ (d & 7)) * 8);\
        Of[df] = __builtin_amdgcn_mfma_f32_32x32x16_f16(vf, pf.v, Of[df], 0, 0, 0);      \
      }                                                                                  \
      __builtin_amdgcn_s_setprio(0);                                                     \
    }                                                                                    \
  }

  STAGE(0, 0);
  asm volatile("s_waitcnt vmcnt(0)" ::: "memory");
  __syncthreads();

  int cur = 0;
  for (int t = 0; t < N_ / 64; ++t) {
    if (t < N_ / 64 - 1) STAGE(t + 1, cur ^ 1);
    const f16* Ks = &lds[cur][0][0];
    const f16* Vs = &lds[cur][1][0];

    f32x16 sa0, sa1;
#pragma unroll
    for (int r = 0; r < 16; ++r) { sa0[r] = 0.f; sa1[r] = 0.f; }
    const int krow0 = ql, krow1 = 32 + ql;
    __builtin_amdgcn_s_setprio(1);
#pragma unroll
    for (int ks = 0; ks < 4; ++ks) {
      f16x8 kf = *(const f16x8*)(Ks + krow0 * 64 + ((ks * 2 + hi) ^ (krow0 & 7)) * 8);
      sa0 = __builtin_amdgcn_mfma_f32_32x32x16_f16(kf, qf[ks], sa0, 0, 0, 0);
    }
#pragma unroll
    for (int ks = 0; ks < 4; ++ks) {
      f16x8 kf = *(const f16x8*)(Ks + krow1 * 64 + ((ks * 2 + hi) ^ (krow1 & 7)) * 8);
      sa1 = __builtin_amdgcn_mfma_f32_32x32x16_f16(kf, qf[ks], sa1, 0, 0, 0);
    }
    __builtin_amdgcn_s_setprio(0);

    SOFTMAX_CHUNK(sa0);
    PV_CHUNK(sa0, 0);
    SOFTMAX_CHUNK(sa1);
    PV_CHUNK(sa1, 1);

    asm volatile("s_waitcnt vmcnt(0)" ::: "memory");
    __syncthreads();
    cur ^= 1;
  }

  // ---- epilogue: one cross-half l reduce, then LDS transpose -> stores
  const float l_tot = l_run + __shfl_xor(l_run, 32);
  const float inv = 1.0f / l_tot;
  f16* Ow = &lds[0][0][0] + w * (32 * 72);
#pragma unroll
  for (int df = 0; df < 2; ++df)
#pragma unroll
    for (int g = 0; g < 4; ++g) {
      f16x4 ov;
#pragma unroll
      for (int e = 0; e < 4; ++e) ov[e] = (f16)(Of[df][g * 4 + e] * inv);
      *(f16x4*)(Ow + ql * 72 + df * 32 + g * 8 + hi * 4) = ov;
    }
  __syncthreads();
  const int rr = lane >> 1, half = lane & 1;
  const f16* srcp = Ow + rr * 72 + half * 32;
  const int nglob = qb * 64 + w * 32 + rr;
  f16* dst = Y + ((size_t)b * N_ + nglob) * C_ + h * 64 + half * 32;
#pragma unroll
  for (int c2 = 0; c2 < 4; ++c2)
    *(f16x8*)(dst + c2 * 8) = *(const f16x8*)(srcp + c2 * 8);
}

// ---------------------------------------------------------------- launch
extern "C" void kernel_launch(void* const* d_in, const int* in_sizes, int n_in,
                              void* d_out, int out_size, void* d_ws, size_t ws_size,
                              hipStream_t stream) {
  const float* x = (const float*)d_in[0];
  const float* px = (const float*)d_in[1];
  const float* py = (const float*)d_in[2];
  const float* psp = (const float*)d_in[3];
  const void* mask = (const void*)d_in[4];
  const float* Wqkv = (const float*)d_in[5];
  const float* bqkv = (const float*)d_in[6];
  const float* Wproj = (const float*)d_in[7];
  const float* bproj = (const float*)d_in[8];
  float* out = (float*)d_out;
  char* ws = (char*)d_ws;

  f16* xh     = (f16*)(ws + 0);           //  8,388,608
  f16* Wqkvt  = (f16*)(ws + 8388608);     //  6,291,456
  f16* Wprojt = (f16*)(ws + 14680064);    //  2,097,152
  f16* qkvh   = (f16*)(ws + 16777216);    // 25,165,824
  f16* Qh     = (f16*)(ws + 41943040);    //  8,388,608
  f16* Kh     = (f16*)(ws + 50331648);    //  8,388,608
  f16* Vt     = (f16*)(ws + 58720256);    //  8,388,608
  f16* Yh     = (f16*)(ws + 67108864);    //  8,388,608
  int* mflag  = (int*)(ws + 75497472);    //  4
  float* cs_tab = (float*)(ws + 67108864);            // 524,288 (dead Yh region)
  float* sn_tab = (float*)(ws + 67108864 + 524288);   // 524,288

  detect_mask<<<1, 256, 0, stream>>>((const u32*)mask, mflag);
  cvt_x<<<2048, 256, 0, stream>>>(x, xh, (B_ * N_ * C_) / 8);
  phase_tab<<<512, 256, 0, stream>>>(px, py, psp, mask, mflag, cs_tab, sn_tab);
  transpose_cvt<<<dim3(96, 32), dim3(32, 8), 0, stream>>>(Wqkv, Wqkvt, C_, 3 * C_);
  transpose_cvt<<<dim3(32, 32), dim3(32, 8), 0, stream>>>(Wproj, Wprojt, C_, C_);
  gemm_bt<false><<<(4096 / 128) * (3072 / 128), 256, 0, stream>>>(
      xh, Wqkvt, bqkv, (void*)qkvh, 4096, 3072, 1024);
  rope_split<<<256, 256, 0, stream>>>(qkvh, cs_tab, sn_tab, Qh, Kh, Vt);
  attn2<<<1024, 128, 0, stream>>>(Qh, Kh, Vt, Yh);
  gemm_bt<true><<<(4096 / 128) * (1024 / 128), 256, 0, stream>>>(
      Yh, Wprojt, bproj, (void*)out, 4096, 1024, 1024);
}

// Round 12
// 160.200 us; speedup vs baseline: 1.0328x; 1.0328x over previous
//
#include <hip/hip_runtime.h>
#include <hip/hip_fp16.h>

typedef _Float16 f16;
typedef unsigned int u32;
typedef _Float16 f16x4 __attribute__((ext_vector_type(4)));
typedef _Float16 f16x8 __attribute__((ext_vector_type(8)));
typedef float f32x4 __attribute__((ext_vector_type(4)));
typedef float f32x16 __attribute__((ext_vector_type(16)));

#define B_  2
#define N_  2048
#define C_  1024
#define H_  16
#define HD_ 64

// ---------------------------------------------------------------- helpers
__device__ __forceinline__ void gload_lds16(const void* g, void* l) {
  __builtin_amdgcn_global_load_lds((const __attribute__((address_space(1))) u32*)g,
                                   (__attribute__((address_space(3))) u32*)l,
                                   16, 0, 0);
}

__device__ __forceinline__ u32 pack_f16(float a, float b) {
  auto h2 = __builtin_amdgcn_cvt_pkrtz(a, b);   // __fp16 ext_vector(2)
  return __builtin_bit_cast(u32, h2);
}

__device__ __forceinline__ float max3f(float a, float b, float c) {
  return fmaxf(fmaxf(a, b), c);   // clang fuses to v_max3_f32
}

// ---------------------------------------------------------------- mask dtype probe
__global__ void detect_mask(const u32* __restrict__ m, int* __restrict__ flag) {
  __shared__ int bad;
  if (threadIdx.x == 0) bad = 0;
  __syncthreads();
  int v = 0;
  for (int i = threadIdx.x; i < 1024; i += 256) {
    u32 w = m[i];
    if (w != 0u && w != 1u && w != 0x3F800000u) v = 1;
  }
  if (v) atomicOr(&bad, 1);
  __syncthreads();
  if (threadIdx.x == 0) *flag = bad;   // 1 => byte mask, 0 => 4-byte mask
}

// ---------------------------------------------------------------- phase table
__global__ __launch_bounds__(256) void phase_tab(const float* __restrict__ px,
                                                 const float* __restrict__ py,
                                                 const float* __restrict__ psp,
                                                 const void* __restrict__ maskPtr,
                                                 const int* __restrict__ maskFlag,
                                                 float* __restrict__ cs_tab,
                                                 float* __restrict__ sn_tab) {
  const int idx = blockIdx.x * 256 + threadIdx.x;   // (b*N+n)*32 + j
  const int j = idx & 31, tn = idx >> 5;
  const int byteMode = *maskFlag;
  const bool doRope = byteMode ? (((const unsigned char*)maskPtr)[tn] != 0)
                               : (((const u32*)maskPtr)[tn] != 0u);
  float c = 1.f, s = 0.f;
  if (doRope) {
    float ph;
    if (j < 12)      ph = px[tn * 12 + j];
    else if (j < 24) ph = py[tn * 12 + (j - 12)];
    else             ph = psp[tn * 8 + (j - 24)];
    c = __cosf(ph);
    s = __sinf(ph);
  }
  cs_tab[idx] = c;
  sn_tab[idx] = s;
}

// ---------------------------------------------------------------- x f32 -> f16
__global__ __launch_bounds__(256) void cvt_x(const float* __restrict__ in,
                                             f16* __restrict__ out, int n8) {
  const int i = blockIdx.x * 256 + threadIdx.x;
  if (i >= n8) return;
  const float4 a = ((const float4*)in)[i * 2];
  const float4 b = ((const float4*)in)[i * 2 + 1];
  f16x8 o = {(f16)a.x, (f16)a.y, (f16)a.z, (f16)a.w,
             (f16)b.x, (f16)b.y, (f16)b.z, (f16)b.w};
  ((f16x8*)out)[i] = o;
}

// ---------------------------------------------------------------- W (RxC f32) -> Wt (CxR f16)
__global__ __launch_bounds__(256) void transpose_cvt(const float* __restrict__ W,
                                                     f16* __restrict__ Wt,
                                                     int R, int Ccols) {
  __shared__ __align__(16) f16 tile[32][34];
  const int c0 = blockIdx.x * 32, r0 = blockIdx.y * 32;
  const int tx = threadIdx.x, ty = threadIdx.y;  // 32 x 8
#pragma unroll
  for (int k = 0; k < 4; ++k)
    tile[ty + 8 * k][tx] = (f16)W[(size_t)(r0 + ty + 8 * k) * Ccols + c0 + tx];
  __syncthreads();
#pragma unroll
  for (int k = 0; k < 4; ++k)
    Wt[(size_t)(c0 + ty + 8 * k) * R + r0 + tx] = tile[tx][ty + 8 * k];
}

// ---------------------------------------------------------------- GEMM  C = A(MxK) * Bt(NxK)^T + bias
template <bool OUT_F32>
__global__ __launch_bounds__(256) void gemm_bt(const f16* __restrict__ A,
                                               const f16* __restrict__ Bt,
                                               const float* __restrict__ bias,
                                               void* __restrict__ Cout,
                                               int M, int N, int K) {
  __shared__ __align__(16) f16 As[128 * 64];
  __shared__ __align__(16) f16 Bs[128 * 64];
  const int tid = threadIdx.x;
  const int lane = tid & 63;
  const int wv = tid >> 6;
  const int wm = wv >> 1, wn = wv & 1;
  const int nTN = N >> 7;
  int bid = blockIdx.x;
  const int cpx = gridDim.x >> 3;
  bid = (bid & 7) * cpx + (bid >> 3);
  const int tM = bid / nTN, tN = bid % nTN;
  const int rowBase = tM << 7, colBase = tN << 7;
  const int cl = lane & 15, cg = lane >> 4;

  f32x4 acc[4][4];
#pragma unroll
  for (int i = 0; i < 4; ++i)
#pragma unroll
    for (int j = 0; j < 4; ++j) acc[i][j] = (f32x4){0.f, 0.f, 0.f, 0.f};

  const int sR = tid >> 3, sC = tid & 7;

  for (int k0 = 0; k0 < K; k0 += 64) {
#pragma unroll
    for (int is = 0; is < 4; ++is) {
      const int r = is * 32 + sR;
      const int sc = sC ^ (r & 7);
      gload_lds16(A + (size_t)(rowBase + r) * K + k0 + sc * 8, As + is * 2048 + tid * 8);
    }
#pragma unroll
    for (int is = 0; is < 4; ++is) {
      const int r = is * 32 + sR;
      const int sc = sC ^ (r & 7);
      gload_lds16(Bt + (size_t)(colBase + r) * K + k0 + sc * 8, Bs + is * 2048 + tid * 8);
    }
    asm volatile("s_waitcnt vmcnt(0)" ::: "memory");
    __syncthreads();

#pragma unroll
    for (int ks = 0; ks < 2; ++ks) {
      f16x8 af[4], bf[4];
#pragma unroll
      for (int m = 0; m < 4; ++m) {
        const int row = wm * 64 + m * 16 + cl;
        const int ck = (ks * 4 + cg) ^ (row & 7);
        af[m] = *(const f16x8*)(As + row * 64 + ck * 8);
      }
#pragma unroll
      for (int n = 0; n < 4; ++n) {
        const int row = wn * 64 + n * 16 + cl;
        const int ck = (ks * 4 + cg) ^ (row & 7);
        bf[n] = *(const f16x8*)(Bs + row * 64 + ck * 8);
      }
#pragma unroll
      for (int m = 0; m < 4; ++m)
#pragma unroll
        for (int n = 0; n < 4; ++n)
          acc[m][n] = __builtin_amdgcn_mfma_f32_16x16x32_f16(af[m], bf[n], acc[m][n], 0, 0, 0);
    }
    __syncthreads();
  }

#pragma unroll
  for (int m = 0; m < 4; ++m) {
#pragma unroll
    for (int n = 0; n < 4; ++n) {
      const int gr0 = rowBase + wm * 64 + m * 16 + cg * 4;
      const int gc = colBase + wn * 64 + n * 16 + cl;
      const float bz = bias[gc];
#pragma unroll
      for (int reg = 0; reg < 4; ++reg) {
        const float v = acc[m][n][reg] + bz;
        if (OUT_F32)
          ((float*)Cout)[(size_t)(gr0 + reg) * N + gc] = v;
        else
          ((f16*)Cout)[(size_t)(gr0 + reg) * N + gc] = (f16)v;
      }
    }
  }
}

// ---------------------------------------------------------------- RoPE + split (table-driven)
__global__ __launch_bounds__(256) void rope_split(const f16* __restrict__ qkv,
                                                  const float* __restrict__ cs_tab,
                                                  const float* __restrict__ sn_tab,
                                                  f16* __restrict__ Qh,
                                                  f16* __restrict__ Kh,
                                                  f16* __restrict__ Vt) {
  __shared__ float cs[64][32], sn[64][32];
  __shared__ __align__(16) f16 vtile[64][72];
  const int tid = threadIdx.x;
  const int blk = blockIdx.x;
  const int hg = blk & 3;
  const int nt = (blk >> 2) & 31;
  const int b = blk >> 7;
  const int n0 = nt * 64;

  for (int i = tid; i < 64 * 32; i += 256) {
    const int tk = i >> 5, j = i & 31;
    const size_t gi = ((size_t)b * N_ + n0 + tk) * 32 + j;
    cs[tk][j] = cs_tab[gi];
    sn[tk][j] = sn_tab[gi];
  }
  __syncthreads();

  const int tk = tid >> 2, hl = tid & 3;
  const int h = hg * 4 + hl;
  const int n = n0 + tk;
  const size_t inRow = ((size_t)b * N_ + n) * 3072 + (size_t)h * 64;
  const size_t outRow = (((size_t)(b * H_ + h)) * N_ + n) * 64;

#pragma unroll
  for (int sec = 0; sec < 2; ++sec) {
    const f16* src = qkv + inRow + sec * 1024;
    float t[64];
#pragma unroll
    for (int c = 0; c < 8; ++c) {
      f16x8 v = *(const f16x8*)(src + c * 8);
#pragma unroll
      for (int j = 0; j < 8; ++j) t[c * 8 + j] = (float)v[j];
    }
    __align__(16) f16 o[64];
#pragma unroll
    for (int d = 0; d < 64; ++d) {
      int j;
      float rot;
      if (d < 24) {
        j = (d < 12) ? d : d - 12;
        rot = (d < 12) ? -t[d + 12] : t[d - 12];
      } else if (d < 48) {
        const int dd = d - 24;
        j = 12 + ((dd < 12) ? dd : dd - 12);
        rot = (dd < 12) ? -t[d + 12] : t[d - 12];
      } else {
        const int dd = d - 48;
        j = 24 + ((dd < 8) ? dd : dd - 8);
        rot = (dd < 8) ? -t[d + 8] : t[d - 8];
      }
      o[d] = (f16)(t[d] * cs[tk][j] + rot * sn[tk][j]);
    }
    f16* dst = (sec == 0 ? Qh : Kh) + outRow;
#pragma unroll
    for (int c = 0; c < 8; ++c) *(f16x8*)(dst + c * 8) = *(const f16x8*)(o + c * 8);
  }

  for (int hl2 = 0; hl2 < 4; ++hl2) {
    const int h2 = hg * 4 + hl2;
    __syncthreads();
    {
      const int tk2 = tid >> 2, c2 = tid & 3;
      const size_t srow = ((size_t)b * N_ + n0 + tk2) * 3072 + 2048 + (size_t)h2 * 64 + c2 * 16;
      *(f16x8*)(&vtile[tk2][c2 * 16]) = *(const f16x8*)(qkv + srow);
      *(f16x8*)(&vtile[tk2][c2 * 16 + 8]) = *(const f16x8*)(qkv + srow + 8);
    }
    __syncthreads();
    {
      const int d = tid >> 2, seg = tid & 3;
      __align__(16) f16 tmp[16];
#pragma unroll
      for (int i = 0; i < 16; ++i) tmp[i] = vtile[seg * 16 + i][d];
      const size_t drow = (((size_t)(b * H_ + h2)) * 64 + d) * N_ + n0 + seg * 16;
      *(f16x8*)(Vt + drow) = *(const f16x8*)(tmp);
      *(f16x8*)(Vt + drow + 8) = *(const f16x8*)(tmp + 8);
    }
  }
}

// ---------------------------------------------------------------- flash attention v5
// r10 geometry (256 thr, 4 waves x 32 q-rows, grid 512) + T4 counted-vmcnt:
// 3 LDS buffers, stage t+2 at top of iter t, wait only vmcnt(4) (t+1 done,
// t+2's 4 loads stay in flight) + lgkmcnt(0), then RAW s_barrier (avoids
// __syncthreads' compiler-emitted vmcnt(0) drain). Buf reuse safe: stage(t+2)
// targets buf (t-1)%3 whose readers lgkm-drained before the t-1 barrier.
__global__ __launch_bounds__(256) void attn2(const f16* __restrict__ Qh,
                                             const f16* __restrict__ Kh,
                                             const f16* __restrict__ Vt,
                                             f16* __restrict__ Y) {
  __shared__ __align__(16) f16 lds_flat[3 * 8192];  // 3 bufs x (K 4096 | V 4096)
  const int tid = threadIdx.x, lane = tid & 63, w = tid >> 6;
  int bid = blockIdx.x;
  bid = (bid & 7) * 64 + (bid >> 3);  // XCD-chunked swizzle (512 % 8 == 0)
  const int bh = bid >> 4, qb = bid & 15;
  const int b = bh >> 4, h = bh & 15;
  const f16* Qb = Qh + (size_t)bh * N_ * 64;
  const f16* Kb = Kh + (size_t)bh * N_ * 64;
  const f16* Vb = Vt + (size_t)bh * 64 * N_;
  const int ql = lane & 31, hi = lane >> 5;

  f16x8 qf[4];
  {
    const int qrow = qb * 128 + w * 32 + ql;
    const f16 scl = (f16)0.125f;
#pragma unroll
    for (int ks = 0; ks < 4; ++ks) {
      f16x8 v = *(const f16x8*)(Qb + (size_t)qrow * 64 + ks * 16 + hi * 8);
#pragma unroll
      for (int j = 0; j < 8; ++j) v[j] *= scl;
      qf[ks] = v;
    }
  }

  f32x16 Of[2];
#pragma unroll
  for (int d = 0; d < 2; ++d)
#pragma unroll
    for (int r = 0; r < 16; ++r) Of[d][r] = 0.f;
  float m_run = -1e30f, l_run = 0.f;   // l_run per-lane; cross-half reduce deferred

  const int sr = tid >> 3, sc = tid & 7;
  // 4 global_load_lds per thread per stage -> counted wait = vmcnt(4)
#define STAGE(t, bp)                                                                     \
  {                                                                                      \
    _Pragma("unroll") for (int i = 0; i < 2; ++i) {                                      \
      const int row = i * 32 + sr;                                                       \
      const int g = sc ^ (row & 7);                                                      \
      gload_lds16(Kb + (size_t)((t) * 64 + row) * 64 + g * 8, (bp) + i * 2048 + tid * 8);\
    }                                                                                    \
    _Pragma("unroll") for (int i = 0; i < 2; ++i) {                                      \
      const int row = i * 32 + sr;                                                       \
      const int g = sc ^ (row & 7);                                                      \
      gload_lds16(Vb + (size_t)row * N_ + (t) * 64 + g * 8,                              \
                  (bp) + 4096 + i * 2048 + tid * 8);                                     \
    }                                                                                    \
  }

#define SOFTMAX_CHUNK(sa)                                                                \
  {                                                                                      \
    float t0 = max3f(sa[0], sa[1], sa[2]);                                               \
    float t1 = max3f(sa[3], sa[4], sa[5]);                                               \
    float t2 = max3f(sa[6], sa[7], sa[8]);                                               \
    float t3 = max3f(sa[9], sa[10], sa[11]);                                             \
    float t4 = max3f(sa[12], sa[13], sa[14]);                                            \
    float pmax = max3f(max3f(t0, t1, t2), max3f(t3, t4, sa[15]), -1e30f);                \
    pmax = fmaxf(pmax, __shfl_xor(pmax, 32));                                            \
    if (__any(pmax > m_run + 8.0f)) {                                                    \
      const float mnew = fmaxf(m_run, pmax);                                             \
      const float corr = __expf(m_run - mnew);                                           \
      l_run *= corr;                                                                     \
      _Pragma("unroll") for (int d = 0; d < 2; ++d)                                      \
        _Pragma("unroll") for (int r = 0; r < 16; ++r) Of[d][r] *= corr;                 \
      m_run = mnew;                                                                      \
    }                                                                                    \
    _Pragma("unroll") for (int r = 0; r < 16; ++r) sa[r] = __expf(sa[r] - m_run);        \
    float s0 = ((sa[0] + sa[1]) + (sa[2] + sa[3])) + ((sa[4] + sa[5]) + (sa[6] + sa[7]));\
    float s1 = ((sa[8] + sa[9]) + (sa[10] + sa[11])) +                                   \
               ((sa[12] + sa[13]) + (sa[14] + sa[15]));                                  \
    l_run += s0 + s1;                                                                    \
  }

#define PV_CHUNK(sa, s)                                                                  \
  {                                                                                      \
    u32 pw[8];                                                                           \
    _Pragma("unroll") for (int tt = 0; tt < 8; ++tt)                                     \
      pw[tt] = pack_f16(sa[2 * tt], sa[2 * tt + 1]);                                     \
    _Pragma("unroll") for (int kk = 0; kk < 2; ++kk) {                                   \
      u32 a0 = pw[4 * kk], a1 = pw[4 * kk + 1];                                          \
      u32 b0 = pw[4 * kk + 2], b1 = pw[4 * kk + 3];                                      \
      asm volatile("v_permlane32_swap_b32 %0, %1" : "+v"(a0), "+v"(b0));                 \
      asm volatile("v_permlane32_swap_b32 %0, %1" : "+v"(a1), "+v"(b1));                 \
      union { u32 u[4]; f16x8 v; } pf;                                                   \
      pf.u[0] = a0; pf.u[1] = a1; pf.u[2] = b0; pf.u[3] = b1;                            \
      __builtin_amdgcn_s_setprio(1);                                                     \
      _Pragma("unroll") for (int df = 0; df < 2; ++df) {                                 \
        const int d = df * 32 + ql;                                                      \
        f16x8 vf = *(const f16x8*)(Vs + d * 64 + (((s) * 4 + kk * 2 + hi) ^ (d & 7)) * 8);\
        Of[df] = __builtin_amdgcn_mfma_f32_32x32x16_f16(vf, pf.v, Of[df], 0, 0, 0);      \
      }                                                                                  \
      __builtin_amdgcn_s_setprio(0);                                                     \
    }                                                                                    \
  }

  f16* const base = &lds_flat[0];
  STAGE(0, base);
  STAGE(1, base + 8192);
  asm volatile("s_waitcnt vmcnt(4)" ::: "memory");  // tile 0 landed; tile 1 in flight
  __builtin_amdgcn_s_barrier();

  f16* curp = base;
  f16* stagep = base + 16384;
  for (int t = 0; t < N_ / 64; ++t) {
    if (t < N_ / 64 - 2) STAGE(t + 2, stagep);
    const f16* Ks = curp;
    const f16* Vs = curp + 4096;

    f32x16 sa0, sa1;
#pragma unroll
    for (int r = 0; r < 16; ++r) { sa0[r] = 0.f; sa1[r] = 0.f; }
    const int krow0 = ql, krow1 = 32 + ql;
    __builtin_amdgcn_s_setprio(1);
#pragma unroll
    for (int ks = 0; ks < 4; ++ks) {
      f16x8 kf = *(const f16x8*)(Ks + krow0 * 64 + ((ks * 2 + hi) ^ (krow0 & 7)) * 8);
      sa0 = __builtin_amdgcn_mfma_f32_32x32x16_f16(kf, qf[ks], sa0, 0, 0, 0);
    }
#pragma unroll
    for (int ks = 0; ks < 4; ++ks) {
      f16x8 kf = *(const f16x8*)(Ks + krow1 * 64 + ((ks * 2 + hi) ^ (krow1 & 7)) * 8);
      sa1 = __builtin_amdgcn_mfma_f32_32x32x16_f16(kf, qf[ks], sa1, 0, 0, 0);
    }
    __builtin_amdgcn_s_setprio(0);

    SOFTMAX_CHUNK(sa0);
    PV_CHUNK(sa0, 0);
    SOFTMAX_CHUNK(sa1);
    PV_CHUNK(sa1, 1);

    // counted wait: t+1's 4 loads done, t+2's 4 stay in flight (never drain)
    if (t < N_ / 64 - 2)
      asm volatile("s_waitcnt vmcnt(4) lgkmcnt(0)" ::: "memory");
    else if (t < N_ / 64 - 1)
      asm volatile("s_waitcnt vmcnt(0) lgkmcnt(0)" ::: "memory");
    else
      asm volatile("s_waitcnt lgkmcnt(0)" ::: "memory");
    __builtin_amdgcn_s_barrier();
    curp = (curp == base + 16384) ? base : curp + 8192;
    stagep = (stagep == base + 16384) ? base : stagep + 8192;
  }

  // ---- epilogue: one cross-half l reduce, LDS transpose -> coalesced stores
  const float l_tot = l_run + __shfl_xor(l_run, 32);
  const float inv = 1.0f / l_tot;
  f16* Ow = base + w * (32 * 72);
#pragma unroll
  for (int df = 0; df < 2; ++df)
#pragma unroll
    for (int g = 0; g < 4; ++g) {
      f16x4 ov;
#pragma unroll
      for (int e = 0; e < 4; ++e) ov[e] = (f16)(Of[df][g * 4 + e] * inv);
      *(f16x4*)(Ow + ql * 72 + df * 32 + g * 8 + hi * 4) = ov;
    }
  __syncthreads();
  const int rr = lane >> 1, half = lane & 1;
  const f16* srcp = Ow + rr * 72 + half * 32;
  const int nglob = qb * 128 + w * 32 + rr;
  f16* dst = Y + ((size_t)b * N_ + nglob) * C_ + h * 64 + half * 32;
#pragma unroll
  for (int c2 = 0; c2 < 4; ++c2)
    *(f16x8*)(dst + c2 * 8) = *(const f16x8*)(srcp + c2 * 8);
}

// ---------------------------------------------------------------- launch
extern "C" void kernel_launch(void* const* d_in, const int* in_sizes, int n_in,
                              void* d_out, int out_size, void* d_ws, size_t ws_size,
                              hipStream_t stream) {
  const float* x = (const float*)d_in[0];
  const float* px = (const float*)d_in[1];
  const float* py = (const float*)d_in[2];
  const float* psp = (const float*)d_in[3];
  const void* mask = (const void*)d_in[4];
  const float* Wqkv = (const float*)d_in[5];
  const float* bqkv = (const float*)d_in[6];
  const float* Wproj = (const float*)d_in[7];
  const float* bproj = (const float*)d_in[8];
  float* out = (float*)d_out;
  char* ws = (char*)d_ws;

  f16* xh     = (f16*)(ws + 0);           //  8,388,608
  f16* Wqkvt  = (f16*)(ws + 8388608);     //  6,291,456
  f16* Wprojt = (f16*)(ws + 14680064);    //  2,097,152
  f16* qkvh   = (f16*)(ws + 16777216);    // 25,165,824
  f16* Qh     = (f16*)(ws + 41943040);    //  8,388,608
  f16* Kh     = (f16*)(ws + 50331648);    //  8,388,608
  f16* Vt     = (f16*)(ws + 58720256);    //  8,388,608
  f16* Yh     = (f16*)(ws + 67108864);    //  8,388,608
  int* mflag  = (int*)(ws + 75497472);    //  4
  float* cs_tab = (float*)(ws + 67108864);            // 524,288 (dead Yh region)
  float* sn_tab = (float*)(ws + 67108864 + 524288);   // 524,288

  detect_mask<<<1, 256, 0, stream>>>((const u32*)mask, mflag);
  cvt_x<<<2048, 256, 0, stream>>>(x, xh, (B_ * N_ * C_) / 8);
  phase_tab<<<512, 256, 0, stream>>>(px, py, psp, mask, mflag, cs_tab, sn_tab);
  transpose_cvt<<<dim3(96, 32), dim3(32, 8), 0, stream>>>(Wqkv, Wqkvt, C_, 3 * C_);
  transpose_cvt<<<dim3(32, 32), dim3(32, 8), 0, stream>>>(Wproj, Wprojt, C_, C_);
  gemm_bt<false><<<(4096 / 128) * (3072 / 128), 256, 0, stream>>>(
      xh, Wqkvt, bqkv, (void*)qkvh, 4096, 3072, 1024);
  rope_split<<<256, 256, 0, stream>>>(qkvh, cs_tab, sn_tab, Qh, Kh, Vt);
  attn2<<<512, 256, 0, stream>>>(Qh, Kh, Vt, Yh);
  gemm_bt<true><<<(4096 / 128) * (1024 / 128), 256, 0, stream>>>(
      Yh, Wprojt, bproj, (void*)out, 4096, 1024, 1024);
}

// Round 13
// 153.066 us; speedup vs baseline: 1.0810x; 1.0466x over previous
//
#include <hip/hip_runtime.h>
#include <hip/hip_fp16.h>

typedef _Float16 f16;
typedef unsigned int u32;
typedef _Float16 f16x4 __attribute__((ext_vector_type(4)));
typedef _Float16 f16x8 __attribute__((ext_vector_type(8)));
typedef float f32x4 __attribute__((ext_vector_type(4)));
typedef float f32x16 __attribute__((ext_vector_type(16)));

#define B_  2
#define N_  2048
#define C_  1024
#define H_  16
#define HD_ 64

// ---------------------------------------------------------------- helpers
__device__ __forceinline__ void gload_lds16(const void* g, void* l) {
  __builtin_amdgcn_global_load_lds((const __attribute__((address_space(1))) u32*)g,
                                   (__attribute__((address_space(3))) u32*)l,
                                   16, 0, 0);
}

__device__ __forceinline__ u32 pack_f16(float a, float b) {
  auto h2 = __builtin_amdgcn_cvt_pkrtz(a, b);   // __fp16 ext_vector(2)
  return __builtin_bit_cast(u32, h2);
}

__device__ __forceinline__ float max3f(float a, float b, float c) {
  return fmaxf(fmaxf(a, b), c);   // clang fuses to v_max3_f32
}

// ---------------------------------------------------------------- mask dtype probe
__global__ void detect_mask(const u32* __restrict__ m, int* __restrict__ flag) {
  __shared__ int bad;
  if (threadIdx.x == 0) bad = 0;
  __syncthreads();
  int v = 0;
  for (int i = threadIdx.x; i < 1024; i += 256) {
    u32 w = m[i];
    if (w != 0u && w != 1u && w != 0x3F800000u) v = 1;
  }
  if (v) atomicOr(&bad, 1);
  __syncthreads();
  if (threadIdx.x == 0) *flag = bad;   // 1 => byte mask, 0 => 4-byte mask
}

// ---------------------------------------------------------------- phase table
__global__ __launch_bounds__(256) void phase_tab(const float* __restrict__ px,
                                                 const float* __restrict__ py,
                                                 const float* __restrict__ psp,
                                                 const void* __restrict__ maskPtr,
                                                 const int* __restrict__ maskFlag,
                                                 float* __restrict__ cs_tab,
                                                 float* __restrict__ sn_tab) {
  const int idx = blockIdx.x * 256 + threadIdx.x;   // (b*N+n)*32 + j
  const int j = idx & 31, tn = idx >> 5;
  const int byteMode = *maskFlag;
  const bool doRope = byteMode ? (((const unsigned char*)maskPtr)[tn] != 0)
                               : (((const u32*)maskPtr)[tn] != 0u);
  float c = 1.f, s = 0.f;
  if (doRope) {
    float ph;
    if (j < 12)      ph = px[tn * 12 + j];
    else if (j < 24) ph = py[tn * 12 + (j - 12)];
    else             ph = psp[tn * 8 + (j - 24)];
    c = __cosf(ph);
    s = __sinf(ph);
  }
  cs_tab[idx] = c;
  sn_tab[idx] = s;
}

// ---------------------------------------------------------------- x f32 -> f16
__global__ __launch_bounds__(256) void cvt_x(const float* __restrict__ in,
                                             f16* __restrict__ out, int n8) {
  const int i = blockIdx.x * 256 + threadIdx.x;
  if (i >= n8) return;
  const float4 a = ((const float4*)in)[i * 2];
  const float4 b = ((const float4*)in)[i * 2 + 1];
  f16x8 o = {(f16)a.x, (f16)a.y, (f16)a.z, (f16)a.w,
             (f16)b.x, (f16)b.y, (f16)b.z, (f16)b.w};
  ((f16x8*)out)[i] = o;
}

// ---------------------------------------------------------------- W (RxC f32) -> Wt (CxR f16)
__global__ __launch_bounds__(256) void transpose_cvt(const float* __restrict__ W,
                                                     f16* __restrict__ Wt,
                                                     int R, int Ccols) {
  __shared__ __align__(16) f16 tile[32][34];
  const int c0 = blockIdx.x * 32, r0 = blockIdx.y * 32;
  const int tx = threadIdx.x, ty = threadIdx.y;  // 32 x 8
#pragma unroll
  for (int k = 0; k < 4; ++k)
    tile[ty + 8 * k][tx] = (f16)W[(size_t)(r0 + ty + 8 * k) * Ccols + c0 + tx];
  __syncthreads();
#pragma unroll
  for (int k = 0; k < 4; ++k)
    Wt[(size_t)(c0 + ty + 8 * k) * R + r0 + tx] = tile[tx][ty + 8 * k];
}

// ---------------------------------------------------------------- fused QKV GEMM + bias + rope + split
// C = xh(4096x1024) * Wqkvt^T(3072x1024) + bqkv, then per 128x128 tile:
// sec = colBase>>10 (tile never straddles: 1024 % 128 == 0).
//   sec 0/1 (q/k): rope via cs/sn tables -> Qh/Kh [b,h,n,64]
//   sec 2   (v)  : transpose -> Vt [b,h,64,n]
// Rounding path bit-identical to old gemm->qkvh(f16)->rope_split chain.
__global__ __launch_bounds__(256) void gemm_qkv(const f16* __restrict__ A,
                                                const f16* __restrict__ Bt,
                                                const float* __restrict__ bias,
                                                const float* __restrict__ cs_tab,
                                                const float* __restrict__ sn_tab,
                                                f16* __restrict__ Qh,
                                                f16* __restrict__ Kh,
                                                f16* __restrict__ Vt) {
  __shared__ __align__(16) f16 smem[128 * 130];   // K-loop: As=smem, Bs=smem+8192; epilogue: [128][130] tile
  f16* const As = smem;
  f16* const Bs = smem + 8192;
  const int K = 1024, Ncols = 3072;
  const int tid = threadIdx.x;
  const int lane = tid & 63;
  const int wv = tid >> 6;
  const int wm = wv >> 1, wn = wv & 1;
  const int nTN = Ncols >> 7;
  int bid = blockIdx.x;
  const int cpx = gridDim.x >> 3;
  bid = (bid & 7) * cpx + (bid >> 3);   // XCD swizzle (768 % 8 == 0, bijective)
  const int tM = bid / nTN, tN = bid % nTN;
  const int rowBase = tM << 7, colBase = tN << 7;
  const int cl = lane & 15, cg = lane >> 4;

  f32x4 acc[4][4];
#pragma unroll
  for (int i = 0; i < 4; ++i)
#pragma unroll
    for (int j = 0; j < 4; ++j) acc[i][j] = (f32x4){0.f, 0.f, 0.f, 0.f};

  const int sR = tid >> 3, sC = tid & 7;

  for (int k0 = 0; k0 < K; k0 += 64) {
#pragma unroll
    for (int is = 0; is < 4; ++is) {
      const int r = is * 32 + sR;
      const int sc = sC ^ (r & 7);
      gload_lds16(A + (size_t)(rowBase + r) * K + k0 + sc * 8, As + is * 2048 + tid * 8);
    }
#pragma unroll
    for (int is = 0; is < 4; ++is) {
      const int r = is * 32 + sR;
      const int sc = sC ^ (r & 7);
      gload_lds16(Bt + (size_t)(colBase + r) * K + k0 + sc * 8, Bs + is * 2048 + tid * 8);
    }
    asm volatile("s_waitcnt vmcnt(0)" ::: "memory");
    __syncthreads();

#pragma unroll
    for (int ks = 0; ks < 2; ++ks) {
      f16x8 af[4], bf[4];
#pragma unroll
      for (int m = 0; m < 4; ++m) {
        const int row = wm * 64 + m * 16 + cl;
        const int ck = (ks * 4 + cg) ^ (row & 7);
        af[m] = *(const f16x8*)(As + row * 64 + ck * 8);
      }
#pragma unroll
      for (int n = 0; n < 4; ++n) {
        const int row = wn * 64 + n * 16 + cl;
        const int ck = (ks * 4 + cg) ^ (row & 7);
        bf[n] = *(const f16x8*)(Bs + row * 64 + ck * 8);
      }
#pragma unroll
      for (int m = 0; m < 4; ++m)
#pragma unroll
        for (int n = 0; n < 4; ++n)
          acc[m][n] = __builtin_amdgcn_mfma_f32_16x16x32_f16(af[m], bf[n], acc[m][n], 0, 0, 0);
    }
    __syncthreads();   // all As/Bs readers done -> safe to repurpose smem
  }

  // ---- epilogue: acc+bias -> f16 LDS tile [128][130] (pitch 65 dwords, odd)
#pragma unroll
  for (int m = 0; m < 4; ++m)
#pragma unroll
    for (int n = 0; n < 4; ++n) {
      const int lc = wn * 64 + n * 16 + cl;
      const float bz = bias[colBase + lc];
#pragma unroll
      for (int reg = 0; reg < 4; ++reg) {
        const int lr = wm * 64 + m * 16 + cg * 4 + reg;
        smem[lr * 130 + lc] = (f16)(acc[m][n][reg] + bz);
      }
    }
  __syncthreads();

  const int sec = colBase >> 10;          // 0=q 1=k 2=v
  const int h0 = (colBase & 1023) >> 6;   // first of 2 heads in this tile
  const int bb = rowBase >> 11;           // batch (2048 % 128 == 0)
  const int nbase = rowBase & 2047;

  if (sec < 2) {
    // q/k: per-thread one (row, head); rope via tables
    const int lr = tid >> 1, hh = tid & 1;
    const int n = nbase + lr;
    const int h = h0 + hh;
    const f16* srcrow = smem + lr * 130 + hh * 64;
    float t[64];
#pragma unroll
    for (int c = 0; c < 8; ++c) {
      f16x8 v = *(const f16x8*)(srcrow + c * 8);
#pragma unroll
      for (int j = 0; j < 8; ++j) t[c * 8 + j] = (float)v[j];
    }
    const float* csr = cs_tab + ((size_t)bb * N_ + n) * 32;
    const float* snr = sn_tab + ((size_t)bb * N_ + n) * 32;
    __align__(16) f16 o[64];
#pragma unroll
    for (int d = 0; d < 64; ++d) {
      int j;
      float rot;
      if (d < 24) {
        j = (d < 12) ? d : d - 12;
        rot = (d < 12) ? -t[d + 12] : t[d - 12];
      } else if (d < 48) {
        const int dd = d - 24;
        j = 12 + ((dd < 12) ? dd : dd - 12);
        rot = (dd < 12) ? -t[d + 12] : t[d - 12];
      } else {
        const int dd = d - 48;
        j = 24 + ((dd < 8) ? dd : dd - 8);
        rot = (dd < 8) ? -t[d + 8] : t[d - 8];
      }
      o[d] = (f16)(t[d] * csr[j] + rot * snr[j]);
    }
    f16* dst = (sec == 0 ? Qh : Kh) + (((size_t)(bb * H_ + h)) * N_ + n) * 64;
#pragma unroll
    for (int c = 0; c < 8; ++c) *(f16x8*)(dst + c * 8) = *(const f16x8*)(o + c * 8);
  } else {
    // v: transpose; per-thread one (head,dim) x 64 rows (column read, 2-way alias = free)
    const int pr = tid >> 1, half = tid & 1;
    const int hh = pr >> 6, d = pr & 63;
    const int h = h0 + hh;
    __align__(16) f16 o[64];
#pragma unroll
    for (int i = 0; i < 64; ++i) o[i] = smem[(half * 64 + i) * 130 + hh * 64 + d];
    f16* dst = Vt + (((size_t)(bb * H_ + h)) * 64 + d) * N_ + nbase + half * 64;
#pragma unroll
    for (int c = 0; c < 8; ++c) *(f16x8*)(dst + c * 8) = *(const f16x8*)(o + c * 8);
  }
}

// ---------------------------------------------------------------- GEMM  C = A(MxK) * Bt(NxK)^T + bias (f32 out)
__global__ __launch_bounds__(256) void gemm_bt_f32(const f16* __restrict__ A,
                                                   const f16* __restrict__ Bt,
                                                   const float* __restrict__ bias,
                                                   float* __restrict__ Cout,
                                                   int M, int N, int K) {
  __shared__ __align__(16) f16 As[128 * 64];
  __shared__ __align__(16) f16 Bs[128 * 64];
  const int tid = threadIdx.x;
  const int lane = tid & 63;
  const int wv = tid >> 6;
  const int wm = wv >> 1, wn = wv & 1;
  const int nTN = N >> 7;
  int bid = blockIdx.x;
  const int cpx = gridDim.x >> 3;
  bid = (bid & 7) * cpx + (bid >> 3);
  const int tM = bid / nTN, tN = bid % nTN;
  const int rowBase = tM << 7, colBase = tN << 7;
  const int cl = lane & 15, cg = lane >> 4;

  f32x4 acc[4][4];
#pragma unroll
  for (int i = 0; i < 4; ++i)
#pragma unroll
    for (int j = 0; j < 4; ++j) acc[i][j] = (f32x4){0.f, 0.f, 0.f, 0.f};

  const int sR = tid >> 3, sC = tid & 7;

  for (int k0 = 0; k0 < K; k0 += 64) {
#pragma unroll
    for (int is = 0; is < 4; ++is) {
      const int r = is * 32 + sR;
      const int sc = sC ^ (r & 7);
      gload_lds16(A + (size_t)(rowBase + r) * K + k0 + sc * 8, As + is * 2048 + tid * 8);
    }
#pragma unroll
    for (int is = 0; is < 4; ++is) {
      const int r = is * 32 + sR;
      const int sc = sC ^ (r & 7);
      gload_lds16(Bt + (size_t)(colBase + r) * K + k0 + sc * 8, Bs + is * 2048 + tid * 8);
    }
    asm volatile("s_waitcnt vmcnt(0)" ::: "memory");
    __syncthreads();

#pragma unroll
    for (int ks = 0; ks < 2; ++ks) {
      f16x8 af[4], bf[4];
#pragma unroll
      for (int m = 0; m < 4; ++m) {
        const int row = wm * 64 + m * 16 + cl;
        const int ck = (ks * 4 + cg) ^ (row & 7);
        af[m] = *(const f16x8*)(As + row * 64 + ck * 8);
      }
#pragma unroll
      for (int n = 0; n < 4; ++n) {
        const int row = wn * 64 + n * 16 + cl;
        const int ck = (ks * 4 + cg) ^ (row & 7);
        bf[n] = *(const f16x8*)(Bs + row * 64 + ck * 8);
      }
#pragma unroll
      for (int m = 0; m < 4; ++m)
#pragma unroll
        for (int n = 0; n < 4; ++n)
          acc[m][n] = __builtin_amdgcn_mfma_f32_16x16x32_f16(af[m], bf[n], acc[m][n], 0, 0, 0);
    }
    __syncthreads();
  }

#pragma unroll
  for (int m = 0; m < 4; ++m) {
#pragma unroll
    for (int n = 0; n < 4; ++n) {
      const int gr0 = rowBase + wm * 64 + m * 16 + cg * 4;
      const int gc = colBase + wn * 64 + n * 16 + cl;
      const float bz = bias[gc];
#pragma unroll
      for (int reg = 0; reg < 4; ++reg)
        Cout[(size_t)(gr0 + reg) * N + gc] = acc[m][n][reg] + bz;
    }
  }
}

// ---------------------------------------------------------------- flash attention v5 (r12, passing)
__global__ __launch_bounds__(256) void attn2(const f16* __restrict__ Qh,
                                             const f16* __restrict__ Kh,
                                             const f16* __restrict__ Vt,
                                             f16* __restrict__ Y) {
  __shared__ __align__(16) f16 lds_flat[3 * 8192];  // 3 bufs x (K 4096 | V 4096)
  const int tid = threadIdx.x, lane = tid & 63, w = tid >> 6;
  int bid = blockIdx.x;
  bid = (bid & 7) * 64 + (bid >> 3);  // XCD-chunked swizzle (512 % 8 == 0)
  const int bh = bid >> 4, qb = bid & 15;
  const int b = bh >> 4, h = bh & 15;
  const f16* Qb = Qh + (size_t)bh * N_ * 64;
  const f16* Kb = Kh + (size_t)bh * N_ * 64;
  const f16* Vb = Vt + (size_t)bh * 64 * N_;
  const int ql = lane & 31, hi = lane >> 5;

  f16x8 qf[4];
  {
    const int qrow = qb * 128 + w * 32 + ql;
    const f16 scl = (f16)0.125f;
#pragma unroll
    for (int ks = 0; ks < 4; ++ks) {
      f16x8 v = *(const f16x8*)(Qb + (size_t)qrow * 64 + ks * 16 + hi * 8);
#pragma unroll
      for (int j = 0; j < 8; ++j) v[j] *= scl;
      qf[ks] = v;
    }
  }

  f32x16 Of[2];
#pragma unroll
  for (int d = 0; d < 2; ++d)
#pragma unroll
    for (int r = 0; r < 16; ++r) Of[d][r] = 0.f;
  float m_run = -1e30f, l_run = 0.f;   // l_run per-lane; cross-half reduce deferred

  const int sr = tid >> 3, sc = tid & 7;
#define STAGE(t, bp)                                                                     \
  {                                                                                      \
    _Pragma("unroll") for (int i = 0; i < 2; ++i) {                                      \
      const int row = i * 32 + sr;                                                       \
      const int g = sc ^ (row & 7);                                                      \
      gload_lds16(Kb + (size_t)((t) * 64 + row) * 64 + g * 8, (bp) + i * 2048 + tid * 8);\
    }                                                                                    \
    _Pragma("unroll") for (int i = 0; i < 2; ++i) {                                      \
      const int row = i * 32 + sr;                                                       \
      const int g = sc ^ (row & 7);                                                      \
      gload_lds16(Vb + (size_t)row * N_ + (t) * 64 + g * 8,                              \
                  (bp) + 4096 + i * 2048 + tid * 8);                                     \
    }                                                                                    \
  }

#define SOFTMAX_CHUNK(sa)                                                                \
  {                                                                                      \
    float t0 = max3f(sa[0], sa[1], sa[2]);                                               \
    float t1 = max3f(sa[3], sa[4], sa[5]);                                               \
    float t2 = max3f(sa[6], sa[7], sa[8]);                                               \
    float t3 = max3f(sa[9], sa[10], sa[11]);                                             \
    float t4 = max3f(sa[12], sa[13], sa[14]);                                            \
    float pmax = max3f(max3f(t0, t1, t2), max3f(t3, t4, sa[15]), -1e30f);                \
    pmax = fmaxf(pmax, __shfl_xor(pmax, 32));                                            \
    if (__any(pmax > m_run + 8.0f)) {                                                    \
      const float mnew = fmaxf(m_run, pmax);                                             \
      const float corr = __expf(m_run - mnew);                                           \
      l_run *= corr;                                                                     \
      _Pragma("unroll") for (int d = 0; d < 2; ++d)                                      \
        _Pragma("unroll") for (int r = 0; r < 16; ++r) Of[d][r] *= corr;                 \
      m_run = mnew;                                                                      \
    }                                                                                    \
    _Pragma("unroll") for (int r = 0; r < 16; ++r) sa[r] = __expf(sa[r] - m_run);        \
    float s0 = ((sa[0] + sa[1]) + (sa[2] + sa[3])) + ((sa[4] + sa[5]) + (sa[6] + sa[7]));\
    float s1 = ((sa[8] + sa[9]) + (sa[10] + sa[11])) +                                   \
               ((sa[12] + sa[13]) + (sa[14] + sa[15]));                                  \
    l_run += s0 + s1;                                                                    \
  }

#define PV_CHUNK(sa, s)                                                                  \
  {                                                                                      \
    u32 pw[8];                                                                           \
    _Pragma("unroll") for (int tt = 0; tt < 8; ++tt)                                     \
      pw[tt] = pack_f16(sa[2 * tt], sa[2 * tt + 1]);                                     \
    _Pragma("unroll") for (int kk = 0; kk < 2; ++kk) {                                   \
      u32 a0 = pw[4 * kk], a1 = pw[4 * kk + 1];                                          \
      u32 b0 = pw[4 * kk + 2], b1 = pw[4 * kk + 3];                                      \
      asm volatile("v_permlane32_swap_b32 %0, %1" : "+v"(a0), "+v"(b0));                 \
      asm volatile("v_permlane32_swap_b32 %0, %1" : "+v"(a1), "+v"(b1));                 \
      union { u32 u[4]; f16x8 v; } pf;                                                   \
      pf.u[0] = a0; pf.u[1] = a1; pf.u[2] = b0; pf.u[3] = b1;                            \
      __builtin_amdgcn_s_setprio(1);                                                     \
      _Pragma("unroll") for (int df = 0; df < 2; ++df) {                                 \
        const int d = df * 32 + ql;                                                      \
        f16x8 vf = *(const f16x8*)(Vs + d * 64 + (((s) * 4 + kk * 2 + hi) ^ (d & 7)) * 8);\
        Of[df] = __builtin_amdgcn_mfma_f32_32x32x16_f16(vf, pf.v, Of[df], 0, 0, 0);      \
      }                                                                                  \
      __builtin_amdgcn_s_setprio(0);                                                     \
    }                                                                                    \
  }

  f16* const base = &lds_flat[0];
  STAGE(0, base);
  STAGE(1, base + 8192);
  asm volatile("s_waitcnt vmcnt(4)" ::: "memory");  // tile 0 landed; tile 1 in flight
  __builtin_amdgcn_s_barrier();

  f16* curp = base;
  f16* stagep = base + 16384;
  for (int t = 0; t < N_ / 64; ++t) {
    if (t < N_ / 64 - 2) STAGE(t + 2, stagep);
    const f16* Ks = curp;
    const f16* Vs = curp + 4096;

    f32x16 sa0, sa1;
#pragma unroll
    for (int r = 0; r < 16; ++r) { sa0[r] = 0.f; sa1[r] = 0.f; }
    const int krow0 = ql, krow1 = 32 + ql;
    __builtin_amdgcn_s_setprio(1);
#pragma unroll
    for (int ks = 0; ks < 4; ++ks) {
      f16x8 kf = *(const f16x8*)(Ks + krow0 * 64 + ((ks * 2 + hi) ^ (krow0 & 7)) * 8);
      sa0 = __builtin_amdgcn_mfma_f32_32x32x16_f16(kf, qf[ks], sa0, 0, 0, 0);
    }
#pragma unroll
    for (int ks = 0; ks < 4; ++ks) {
      f16x8 kf = *(const f16x8*)(Ks + krow1 * 64 + ((ks * 2 + hi) ^ (krow1 & 7)) * 8);
      sa1 = __builtin_amdgcn_mfma_f32_32x32x16_f16(kf, qf[ks], sa1, 0, 0, 0);
    }
    __builtin_amdgcn_s_setprio(0);

    SOFTMAX_CHUNK(sa0);
    PV_CHUNK(sa0, 0);
    SOFTMAX_CHUNK(sa1);
    PV_CHUNK(sa1, 1);

    if (t < N_ / 64 - 2)
      asm volatile("s_waitcnt vmcnt(4) lgkmcnt(0)" ::: "memory");
    else if (t < N_ / 64 - 1)
      asm volatile("s_waitcnt vmcnt(0) lgkmcnt(0)" ::: "memory");
    else
      asm volatile("s_waitcnt lgkmcnt(0)" ::: "memory");
    __builtin_amdgcn_s_barrier();
    curp = (curp == base + 16384) ? base : curp + 8192;
    stagep = (stagep == base + 16384) ? base : stagep + 8192;
  }

  // ---- epilogue: one cross-half l reduce, LDS transpose -> coalesced stores
  const float l_tot = l_run + __shfl_xor(l_run, 32);
  const float inv = 1.0f / l_tot;
  f16* Ow = base + w * (32 * 72);
#pragma unroll
  for (int df = 0; df < 2; ++df)
#pragma unroll
    for (int g = 0; g < 4; ++g) {
      f16x4 ov;
#pragma unroll
      for (int e = 0; e < 4; ++e) ov[e] = (f16)(Of[df][g * 4 + e] * inv);
      *(f16x4*)(Ow + ql * 72 + df * 32 + g * 8 + hi * 4) = ov;
    }
  __syncthreads();
  const int rr = lane >> 1, half = lane & 1;
  const f16* srcp = Ow + rr * 72 + half * 32;
  const int nglob = qb * 128 + w * 32 + rr;
  f16* dst = Y + ((size_t)b * N_ + nglob) * C_ + h * 64 + half * 32;
#pragma unroll
  for (int c2 = 0; c2 < 4; ++c2)
    *(f16x8*)(dst + c2 * 8) = *(const f16x8*)(srcp + c2 * 8);
}

// ---------------------------------------------------------------- launch
extern "C" void kernel_launch(void* const* d_in, const int* in_sizes, int n_in,
                              void* d_out, int out_size, void* d_ws, size_t ws_size,
                              hipStream_t stream) {
  const float* x = (const float*)d_in[0];
  const float* px = (const float*)d_in[1];
  const float* py = (const float*)d_in[2];
  const float* psp = (const float*)d_in[3];
  const void* mask = (const void*)d_in[4];
  const float* Wqkv = (const float*)d_in[5];
  const float* bqkv = (const float*)d_in[6];
  const float* Wproj = (const float*)d_in[7];
  const float* bproj = (const float*)d_in[8];
  float* out = (float*)d_out;
  char* ws = (char*)d_ws;

  f16* xh     = (f16*)(ws + 0);           //  8,388,608
  f16* Wqkvt  = (f16*)(ws + 8388608);     //  6,291,456
  f16* Wprojt = (f16*)(ws + 14680064);    //  2,097,152
  f16* Qh     = (f16*)(ws + 41943040);    //  8,388,608
  f16* Kh     = (f16*)(ws + 50331648);    //  8,388,608
  f16* Vt     = (f16*)(ws + 58720256);    //  8,388,608
  f16* Yh     = (f16*)(ws + 67108864);    //  8,388,608
  int* mflag  = (int*)(ws + 75497472);    //  4
  // tables in the old (now unused) qkvh region — alive from phase_tab to gemm_qkv
  float* cs_tab = (float*)(ws + 16777216);            // 524,288
  float* sn_tab = (float*)(ws + 16777216 + 524288);   // 524,288

  detect_mask<<<1, 256, 0, stream>>>((const u32*)mask, mflag);
  cvt_x<<<2048, 256, 0, stream>>>(x, xh, (B_ * N_ * C_) / 8);
  phase_tab<<<512, 256, 0, stream>>>(px, py, psp, mask, mflag, cs_tab, sn_tab);
  transpose_cvt<<<dim3(96, 32), dim3(32, 8), 0, stream>>>(Wqkv, Wqkvt, C_, 3 * C_);
  transpose_cvt<<<dim3(32, 32), dim3(32, 8), 0, stream>>>(Wproj, Wprojt, C_, C_);
  gemm_qkv<<<(4096 / 128) * (3072 / 128), 256, 0, stream>>>(
      xh, Wqkvt, bqkv, cs_tab, sn_tab, Qh, Kh, Vt);
  attn2<<<512, 256, 0, stream>>>(Qh, Kh, Vt, Yh);
  gemm_bt_f32<<<(4096 / 128) * (1024 / 128), 256, 0, stream>>>(
      Yh, Wprojt, bproj, out, 4096, 1024, 1024);
}